// Round 7
// baseline (172.292 us; speedup 1.0000x reference)
//
#include <hip/hip_runtime.h>
#include <stdint.h>

#define B_ 4
#define C_ 64
#define H_ 96
#define W_ 96
#define HP_ 48
#define WP_ 48
#define N_ (H_*W_)      // 9216
#define M_ (HP_*WP_)    // 2304
#define KD_ 64
#define OD_ 64
#define BN_EPS 1e-5f
#define LOG2E 1.4426950408889634f
#define SHIFT2 28.853900817779268f   // 20 * LOG2E
#define QT_ 48                        // q-tile: 768 blocks = exactly 3/CU
#define QI_ (QT_/16)                  // 3 q-frags per block
#define QB_ (N_/QT_)                  // 192 q-tiles per batch
#define NT_ (M_/64)                   // 36 m-tiles (divisible by 6 — 6x unroll relies on it)

// per-wave LDS strip: K 2048 B + V 2048 B + ea 64 B = 4160 B
#define WSTR_ 4160
// one buffer = 4 waves
#define BUFSTR_ 16640
// 3-buffer ring
#define SMEM_ (3*BUFSTR_)             // 49920

typedef __bf16 bf16_t;
typedef bf16_t bf16x8 __attribute__((ext_vector_type(8)));
typedef bf16_t bf16x4 __attribute__((ext_vector_type(4)));
typedef float f32x4 __attribute__((ext_vector_type(4)));
typedef short short4v __attribute__((ext_vector_type(4)));

static __device__ __forceinline__ unsigned short f2bf(float f) {
    unsigned int u = __builtin_bit_cast(unsigned int, f);
    u += 0x7fffu + ((u >> 16) & 1u);
    return (unsigned short)(u >> 16);
}

static __device__ __forceinline__ f32x4 mfma16_bf16(short4v a, short4v b, f32x4 c) {
#if __has_builtin(__builtin_amdgcn_mfma_f32_16x16x16bf16_1k)
    return __builtin_amdgcn_mfma_f32_16x16x16bf16_1k(a, b, c, 0, 0, 0);
#else
    return c;  // host pass only — never executed on device
#endif
}

// async global->LDS DMA, 16B per lane. LDS dest must be linear per wave.
static __device__ __forceinline__ void gl_lds16(const unsigned short* g, unsigned short* l) {
#if __has_builtin(__builtin_amdgcn_global_load_lds)
    __builtin_amdgcn_global_load_lds(
        (const __attribute__((address_space(1))) unsigned int*)(const void*)g,
        (__attribute__((address_space(3))) unsigned int*)(void*)l, 16, 0, 0);
#endif
}

static __device__ __forceinline__ void setprio1() {
#if __has_builtin(__builtin_amdgcn_s_setprio)
    __builtin_amdgcn_s_setprio(1);
#endif
}
static __device__ __forceinline__ void setprio0() {
#if __has_builtin(__builtin_amdgcn_s_setprio)
    __builtin_amdgcn_s_setprio(0);
#endif
}
static __device__ __forceinline__ void schedbar0() {
#if __has_builtin(__builtin_amdgcn_sched_barrier)
    __builtin_amdgcn_sched_barrier(0);
#endif
}

// ---------------- Kernel 1: fused pool(x,c2) + key conv + edge attention ----------------
__global__ __launch_bounds__(256) void prep_kernel(
    const float* __restrict__ x, const float* __restrict__ c2,
    const float* __restrict__ wq, const float* __restrict__ bq,
    const float* __restrict__ w1, const float* __restrict__ bnw, const float* __restrict__ bnb,
    const float* __restrict__ bnm, const float* __restrict__ bnv,
    const float* __restrict__ w2, const float* __restrict__ b2,
    unsigned short* __restrict__ kb, unsigned short* __restrict__ vb, float* __restrict__ ea) {

    __shared__ float lw1[OD_*2*C_];
    __shared__ float lwq[KD_*C_];
    __shared__ float xs[C_*33];
    __shared__ float c2s[C_*33];
    __shared__ float red[8][32];

    int tid = threadIdx.x;
    int b = blockIdx.x / 72;
    int m0 = (blockIdx.x % 72) * 32;

    for (int i = tid; i < OD_*2*C_; i += 256) lw1[i] = w1[i];
    for (int i = tid; i < KD_*C_; i += 256) lwq[i] = wq[i];
    for (int j = tid; j < 2048; j += 256) {
        int c = j >> 5, p = j & 31;
        int m = m0 + p;
        int hp = m / WP_, wp = m % WP_;
        size_t base = ((size_t)(b*C_ + c)*H_ + 2*hp)*W_ + 2*wp;
        const float* px = x + base;
        float mx = fmaxf(fmaxf(px[0], px[1]), fmaxf(px[W_], px[W_+1]));
        xs[c*33 + p] = mx;
        vb[(size_t)(b*C_ + c)*M_ + m] = f2bf(mx);
        const float* pc = c2 + base;
        c2s[c*33 + p] = fmaxf(fmaxf(pc[0], pc[1]), fmaxf(pc[W_], pc[W_+1]));
    }
    __syncthreads();

    int ml = tid & 31, oz = tid >> 5;
    int m = m0 + ml;

    float h[8] = {0,0,0,0,0,0,0,0};
    for (int c = 0; c < C_; c += 4) {
        float x0 = xs[c*33+ml], x1 = xs[(c+1)*33+ml], x2 = xs[(c+2)*33+ml], x3 = xs[(c+3)*33+ml];
        #pragma unroll
        for (int oi = 0; oi < 8; oi++) {
            const float4 wv = *(const float4*)&lwq[(oz*8 + oi)*C_ + c];
            h[oi] = fmaf(wv.x, x0, fmaf(wv.y, x1, fmaf(wv.z, x2, fmaf(wv.w, x3, h[oi]))));
        }
    }
    unsigned short tmp[8];
    #pragma unroll
    for (int oi = 0; oi < 8; oi++) tmp[oi] = f2bf(h[oi] + bq[oz*8 + oi]);
    *(uint4*)&kb[((size_t)b*M_ + m)*KD_ + oz*8] = *(const uint4*)tmp;

    float g[8] = {0,0,0,0,0,0,0,0};
    for (int c = 0; c < 2*C_; c += 4) {
        const float* srcb = (c < C_) ? &c2s[c*33] : &xs[(c - C_)*33];
        float x0 = srcb[ml], x1 = srcb[33+ml], x2 = srcb[66+ml], x3 = srcb[99+ml];
        #pragma unroll
        for (int oi = 0; oi < 8; oi++) {
            const float4 wv = *(const float4*)&lw1[(oz*8 + oi)*(2*C_) + c];
            g[oi] = fmaf(wv.x, x0, fmaf(wv.y, x1, fmaf(wv.z, x2, fmaf(wv.w, x3, g[oi]))));
        }
    }
    float z = 0.f;
    #pragma unroll
    for (int oi = 0; oi < 8; oi++) {
        int o = oz*8 + oi;
        float sc = bnw[o] * rsqrtf(bnv[o] + BN_EPS);
        float t = (g[oi] - bnm[o]) * sc + bnb[o];
        z += w2[o] * fmaxf(t, 0.f);
    }
    red[oz][ml] = z;
    __syncthreads();
    if (oz == 0) {
        float s = b2[0];
        #pragma unroll
        for (int i = 0; i < 8; i++) s += red[i][ml];
        ea[(size_t)b*M_ + m] = LOG2E / (1.f + __builtin_amdgcn_exp2f(-s * LOG2E));
    }
}

// ---------------- Kernel 2: query conv at full res -> bf16 [b][n][64] ----------------
__global__ __launch_bounds__(256) void qk_kernel(const float* __restrict__ in, const float* __restrict__ wq,
    const float* __restrict__ bq, unsigned short* __restrict__ outb) {
    __shared__ float lw[KD_*C_];
    for (int i = threadIdx.x; i < KD_*C_; i += 256) lw[i] = wq[i];
    __syncthreads();
    int ml = threadIdx.x & 31, oz = threadIdx.x >> 5;
    int pg = blockIdx.x * 32 + ml;
    float h[8] = {0,0,0,0,0,0,0,0};
    const float* src = in + ((size_t)(pg / N_))*C_*N_ + (pg % N_);
    for (int c = 0; c < C_; c += 4) {
        float x0 = src[(size_t)c*N_], x1 = src[(size_t)(c+1)*N_];
        float x2 = src[(size_t)(c+2)*N_], x3 = src[(size_t)(c+3)*N_];
        #pragma unroll
        for (int oi = 0; oi < 8; oi++) {
            const float4 wv = *(const float4*)&lw[(oz*8 + oi)*C_ + c];
            h[oi] = fmaf(wv.x, x0, fmaf(wv.y, x1, fmaf(wv.z, x2, fmaf(wv.w, x3, h[oi]))));
        }
    }
    unsigned short tmp[8];
    #pragma unroll
    for (int oi = 0; oi < 8; oi++) tmp[oi] = f2bf(h[oi] + bq[oz*8 + oi]);
    *(uint4*)&outb[(size_t)pg*KD_ + oz*8] = *(const uint4*)tmp;
}

// ---------------- Kernel 3: flash attention ----------------
// R7: BARRIER-FREE main loop. Each wave stages exactly the K-rows/V-cols/ea
// strip it reads (per-wave private LDS regions) -> no cross-wave deps -> no
// s_barrier in the loop. 3-buffer ring, prefetch distance 2, per-wave
// counted waits: vmcnt(5) steady-state (each STAGE = 5 gl_lds), lgkmcnt(7)
// frag ping-pong (2 kf b128 + 4 va b64 + 1 ea b128). Swizzles on the global
// source (rule #21): K 16B-chunk ^(row&7); V strip [64c][16m] with 1-bit
// 16B-chunk ^((c>>2)&1) (worst 4-way on the 8B va reads - acceptable).
__global__ __launch_bounds__(256, 3) void attn_kernel(
    const unsigned short* __restrict__ qb, const unsigned short* __restrict__ kb,
    const unsigned short* __restrict__ vb, const float* __restrict__ ea,
    const float* __restrict__ x, const float* __restrict__ gamma_p, float* __restrict__ out) {

    // 3 buffers x 4 waves x 4160 B = 49920 B
    // epilogue overlay: o_red 2*48*68*4=26112 + l_red 768 = 26880 B (fits)
    __shared__ __align__(16) char smem[SMEM_];

    int tid = threadIdx.x;
    int wave = tid >> 6, lane = tid & 63, quad = lane >> 4, l16 = lane & 15;
    int blk = blockIdx.x;
    int b = (blk & 7) >> 1;                       // batch pinned to XCD pair
    int n_base = ((blk & 1) * (QB_/2) + (blk >> 3)) * QT_;

    // Q B-frags: B[col = q = qi*16+l16][k = quad*8+j]
    bf16x8 qf[QI_][2];
    #pragma unroll
    for (int qi = 0; qi < QI_; qi++) {
        const unsigned short* qp = qb + ((size_t)b*N_ + n_base + qi*16 + l16)*KD_;
        qf[qi][0] = __builtin_bit_cast(bf16x8, *(const uint4*)(qp + quad*8));
        qf[qi][1] = __builtin_bit_cast(bf16x8, *(const uint4*)(qp + 32 + quad*8));
    }

    f32x4 o2[QI_][4]; // O^T partial: [qi][ct]
    f32x4 lacc[QI_];  // denominator partials via ones-MFMA
    #pragma unroll
    for (int qi = 0; qi < QI_; qi++) {
        lacc[qi] = (f32x4){0.f,0.f,0.f,0.f};
        #pragma unroll
        for (int ct = 0; ct < 4; ct++) o2[qi][ct] = (f32x4){0.f,0.f,0.f,0.f};
    }
    const short one_bf = (short)0x3F80;  // bf16 1.0
    short4v ones = (short4v){one_bf, one_bf, one_bf, one_bf};

    const unsigned short* kbB = kb + (size_t)b*M_*KD_;
    const unsigned short* vbB = vb + (size_t)b*C_*M_;
    const float* eaB = ea + (size_t)b*M_;

    // ---- per-wave staging sources (swizzle baked into the global address) ----
    // K strip: rows wave*16+[0..15], row r stores src chunk (d ^ (r&7)) at dest chunk d
    const unsigned short* kSrc = kbB + (size_t)(wave*16 + (lane>>3))*KD_
                                     + (((lane&7) ^ (lane>>3)) << 3);
    // V strip [c][16 m]: row c stores src 16B-chunk (d ^ ((c>>2)&1)) at dest chunk d
    const unsigned short* vSrc = vbB + (size_t)(lane>>1)*M_ + wave*16
                                     + (((lane&1) ^ ((lane>>3)&1)) << 3);
    char* wbW = smem + wave*WSTR_;     // this wave's strip in buffer 0

    auto STAGE = [&](int mb, char* wbuf) {
        unsigned short* kd = (unsigned short*)wbuf;
        unsigned short* vd = (unsigned short*)(wbuf + 2048);
        unsigned short* ed = (unsigned short*)(wbuf + 4096);
        gl_lds16(kSrc + (size_t)mb*KD_,          kd + lane*8);        // K rows +0..7
        gl_lds16(kSrc + (size_t)(mb + 8)*KD_,    kd + 512 + lane*8);  // K rows +8..15
        gl_lds16(vSrc + mb,                      vd + lane*8);        // V c 0..31
        gl_lds16(vSrc + mb + (size_t)32*M_,      vd + 512 + lane*8);  // V c 32..63
        if (lane < 4)                                                  // ea strip 64B
            gl_lds16((const unsigned short*)(eaB + mb + wave*16) + lane*8, ed + lane*8);
    };

    // ---- prologue: stage tiles 0,1,2 into ring buffers 0,1,2 ----
    STAGE(0,   wbW);
    STAGE(64,  wbW + BUFSTR_);
    STAGE(128, wbW + 2*BUFSTR_);
    asm volatile("s_waitcnt vmcnt(10)" ::: "memory");   // tile0's 5 DMA done
    schedbar0();

    // ---- per-wave read offsets (shorts) ----
    int xsw  = l16 & 7;
    int kOff0 = l16*64 + ((quad ^ xsw) << 3);
    int kOff1 = l16*64 + (((quad + 4) ^ xsw) << 3);
    int vsw  = (l16 >> 2) & 1;
    int vOff0 = (0*16 + l16)*16 + ((((quad>>1) ^ vsw)) << 3) + (quad&1)*4;
    int vOff1 = (1*16 + l16)*16 + ((((quad>>1) ^ vsw)) << 3) + (quad&1)*4;
    int vOff2 = (2*16 + l16)*16 + ((((quad>>1) ^ vsw)) << 3) + (quad&1)*4;
    int vOff3 = (3*16 + l16)*16 + ((((quad>>1) ^ vsw)) << 3) + (quad&1)*4;

    struct FragSet { bf16x8 kf0, kf1; short4v va0, va1, va2, va3; f32x4 e4; };
    FragSet fA, fB;

    // read frag set for tile 0 from buffer 0
    {
        unsigned short* kc_ = (unsigned short*)wbW;
        unsigned short* vc_ = (unsigned short*)(wbW + 2048);
        const float*    ec_ = (const float*)(wbW + 4096);
        fA.e4  = *(const f32x4*)(ec_ + quad*4);
        fA.kf0 = __builtin_bit_cast(bf16x8, *(const uint4*)(kc_ + kOff0));
        fA.kf1 = __builtin_bit_cast(bf16x8, *(const uint4*)(kc_ + kOff1));
        fA.va0 = *(const short4v*)(vc_ + vOff0);
        fA.va1 = *(const short4v*)(vc_ + vOff1);
        fA.va2 = *(const short4v*)(vc_ + vOff2);
        fA.va3 = *(const short4v*)(vc_ + vOff3);
    }
    asm volatile("s_waitcnt lgkmcnt(0)" ::: "memory");
    schedbar0();

// one pipeline step: compute tile T_ from CUR; read T_+1 frags (buffer RB_)
// into NXT; stage T_+3 into buffer SB_. No barriers — per-wave regions only.
#define ATTN_STEP(T_, CUR, NXT, RB_, SB_)                                              \
    {                                                                                  \
        const int t_ = (T_);                                                           \
        if (t_ < NT_ - 1) {                                                            \
            if (t_ + 2 < NT_) { asm volatile("s_waitcnt vmcnt(5)" ::: "memory"); }     \
            else              { asm volatile("s_waitcnt vmcnt(0)" ::: "memory"); }     \
            schedbar0();                                                               \
            {                                                                          \
                char* wbR = wbW + (RB_)*BUFSTR_;                                       \
                unsigned short* kc_ = (unsigned short*)wbR;                            \
                unsigned short* vc_ = (unsigned short*)(wbR + 2048);                   \
                const float*    ec_ = (const float*)(wbR + 4096);                      \
                NXT.e4  = *(const f32x4*)(ec_ + quad*4);                               \
                NXT.kf0 = __builtin_bit_cast(bf16x8, *(const uint4*)(kc_ + kOff0));    \
                NXT.kf1 = __builtin_bit_cast(bf16x8, *(const uint4*)(kc_ + kOff1));    \
                NXT.va0 = *(const short4v*)(vc_ + vOff0);                              \
                NXT.va1 = *(const short4v*)(vc_ + vOff1);                              \
                NXT.va2 = *(const short4v*)(vc_ + vOff2);                              \
                NXT.va3 = *(const short4v*)(vc_ + vOff3);                              \
            }                                                                          \
            schedbar0();                                                               \
            if (t_ + 3 < NT_) { STAGE((t_ + 3)*64, wbW + (SB_)*BUFSTR_); }             \
            schedbar0();                                                               \
            asm volatile("s_waitcnt lgkmcnt(7)" ::: "memory"); /* CUR's reads done */  \
            schedbar0();                                                               \
        } else {                                                                       \
            schedbar0();                                                               \
            asm volatile("s_waitcnt lgkmcnt(0)" ::: "memory");                         \
            schedbar0();                                                               \
        }                                                                              \
        f32x4 st[QI_];                                                                 \
        setprio1();                                                                    \
        _Pragma("unroll")                                                              \
        for (int qi = 0; qi < QI_; qi++) {                                             \
            f32x4 z = (f32x4){0.f,0.f,0.f,0.f};                                        \
            z = __builtin_amdgcn_mfma_f32_16x16x32_bf16(CUR.kf0, qf[qi][0], z, 0, 0, 0); \
            z = __builtin_amdgcn_mfma_f32_16x16x32_bf16(CUR.kf1, qf[qi][1], z, 0, 0, 0); \
            st[qi] = z;                                                                \
        }                                                                              \
        setprio0();                                                                    \
        short4v pk[QI_];                                                               \
        _Pragma("unroll")                                                              \
        for (int qi = 0; qi < QI_; qi++) {                                             \
            f32x4 p;                                                                   \
            p[0] = __builtin_amdgcn_exp2f(fmaf(st[qi][0], CUR.e4[0], -SHIFT2));        \
            p[1] = __builtin_amdgcn_exp2f(fmaf(st[qi][1], CUR.e4[1], -SHIFT2));        \
            p[2] = __builtin_amdgcn_exp2f(fmaf(st[qi][2], CUR.e4[2], -SHIFT2));        \
            p[3] = __builtin_amdgcn_exp2f(fmaf(st[qi][3], CUR.e4[3], -SHIFT2));        \
            pk[qi] = __builtin_bit_cast(short4v, __builtin_convertvector(p, bf16x4));  \
        }                                                                              \
        setprio1();                                                                    \
        _Pragma("unroll")                                                              \
        for (int qi = 0; qi < QI_; qi++) {                                             \
            o2[qi][0] = mfma16_bf16(CUR.va0, pk[qi], o2[qi][0]);                       \
            o2[qi][1] = mfma16_bf16(CUR.va1, pk[qi], o2[qi][1]);                       \
            o2[qi][2] = mfma16_bf16(CUR.va2, pk[qi], o2[qi][2]);                       \
            o2[qi][3] = mfma16_bf16(CUR.va3, pk[qi], o2[qi][3]);                       \
            lacc[qi]  = mfma16_bf16(ones,    pk[qi], lacc[qi]);                        \
        }                                                                              \
        setprio0();                                                                    \
    }

    // t mod 6 -> (read buf (t+1)%3, stage buf t%3) are static per position
    for (int base = 0; base < NT_; base += 6) {
        ATTN_STEP(base + 0, fA, fB, 1, 0);
        ATTN_STEP(base + 1, fB, fA, 2, 1);
        ATTN_STEP(base + 2, fA, fB, 0, 2);
        ATTN_STEP(base + 3, fB, fA, 1, 0);
        ATTN_STEP(base + 4, fA, fB, 2, 1);
        ATTN_STEP(base + 5, fB, fA, 0, 2);
    }
#undef ATTN_STEP

    __syncthreads();   // first cross-wave sync since the prologue

    // ---- epilogue: cross-wave reduction of O^T partials and denominators ----
    float* o_red0 = (float*)smem;            // [48 q][68 c]
    float* o_red1 = o_red0 + QT_*68;
    float* l_red  = o_red1 + QT_*68;         // [4][48]

    if (lane < 16) {
        #pragma unroll
        for (int qi = 0; qi < QI_; qi++) l_red[wave*QT_ + qi*16 + l16] = lacc[qi][0];
    }
    if (wave < 2) {
        float* od = (wave == 0) ? o_red0 : o_red1;
        #pragma unroll
        for (int qi = 0; qi < QI_; qi++)
            #pragma unroll
            for (int ct = 0; ct < 4; ct++)
                *(f32x4*)&od[(qi*16 + l16)*68 + ct*16 + quad*4] = o2[qi][ct];
    }
    __syncthreads();
    if (wave >= 2) {
        float* od = (wave == 2) ? o_red0 : o_red1;
        #pragma unroll
        for (int qi = 0; qi < QI_; qi++)
            #pragma unroll
            for (int ct = 0; ct < 4; ct++) {
                f32x4* p = (f32x4*)&od[(qi*16 + l16)*68 + ct*16 + quad*4];
                *p += o2[qi][ct];
            }
    }
    __syncthreads();
    if (tid < QT_) {
        float s = (l_red[tid] + l_red[QT_ + tid]) + (l_red[2*QT_ + tid] + l_red[3*QT_ + tid]);
        l_red[tid] = 1.f / s;
    }
    __syncthreads();

    float gmm = gamma_p[0];
    int c = tid >> 2, q4 = tid & 3;
    const float* xrow = x + ((size_t)b*C_ + c)*N_ + n_base;
    float* orow = out + ((size_t)b*C_ + c)*N_ + n_base;
    #pragma unroll
    for (int i = 0; i < QI_; i++) {
        int q0 = q4*4 + i*16;
        float4 xv = *(const float4*)(xrow + q0);
        float4 ov;
        float v0 = (o_red0[(q0+0)*68 + c] + o_red1[(q0+0)*68 + c]) * l_red[q0+0];
        float v1 = (o_red0[(q0+1)*68 + c] + o_red1[(q0+1)*68 + c]) * l_red[q0+1];
        float v2 = (o_red0[(q0+2)*68 + c] + o_red1[(q0+2)*68 + c]) * l_red[q0+2];
        float v3 = (o_red0[(q0+3)*68 + c] + o_red1[(q0+3)*68 + c]) * l_red[q0+3];
        ov.x = fmaf(gmm, v0, xv.x);
        ov.y = fmaf(gmm, v1, xv.y);
        ov.z = fmaf(gmm, v2, xv.z);
        ov.w = fmaf(gmm, v3, xv.w);
        *(float4*)(orow + q0) = ov;
    }
}

extern "C" void kernel_launch(void* const* d_in, const int* in_sizes, int n_in,
                              void* d_out, int out_size, void* d_ws, size_t ws_size,
                              hipStream_t stream) {
    const float* c2    = (const float*)d_in[0];
    const float* x     = (const float*)d_in[1];
    const float* w_ea1 = (const float*)d_in[2];
    const float* bn_w  = (const float*)d_in[3];
    const float* bn_b  = (const float*)d_in[4];
    const float* bn_m  = (const float*)d_in[5];
    const float* bn_v  = (const float*)d_in[6];
    const float* w_ea2 = (const float*)d_in[7];
    const float* b_ea2 = (const float*)d_in[8];
    const float* w_q   = (const float*)d_in[9];
    const float* b_q   = (const float*)d_in[10];
    const float* gamma = (const float*)d_in[11];
    float* out = (float*)d_out;

    char* ws = (char*)d_ws;
    float* ea            = (float*)(ws + 0);                // 36864
    unsigned short* qb   = (unsigned short*)(ws + 36864);   // 4718592
    unsigned short* kb   = (unsigned short*)(ws + 4755456); // 1179648
    unsigned short* vb   = (unsigned short*)(ws + 5935104); // 1179648

    prep_kernel<<<dim3((B_*M_)/32), dim3(256), 0, stream>>>(x, c2, w_q, b_q,
        w_ea1, bn_w, bn_b, bn_m, bn_v, w_ea2, b_ea2, kb, vb, ea);
    qk_kernel<<<dim3((B_*N_)/32), dim3(256), 0, stream>>>(x, w_q, b_q, qb);
    attn_kernel<<<dim3(B_*QB_), dim3(256), 0, stream>>>(qb, kb, vb, ea, x, gamma, out);
}

// Round 8
// 152.255 us; speedup vs baseline: 1.1316x; 1.1316x over previous
//
#include <hip/hip_runtime.h>
#include <stdint.h>

#define B_ 4
#define C_ 64
#define H_ 96
#define W_ 96
#define HP_ 48
#define WP_ 48
#define N_ (H_*W_)      // 9216
#define M_ (HP_*WP_)    // 2304
#define KD_ 64
#define OD_ 64
#define BN_EPS 1e-5f
#define LOG2E 1.4426950408889634f
#define SHIFT2 28.853900817779268f   // 20 * LOG2E
#define QT_ 48                        // q-tile: 768 blocks = exactly 3/CU
#define QI_ (QT_/16)                  // 3 q-frags per block
#define QB_ (N_/QT_)                  // 192 q-tiles per batch
#define NT_ (M_/64)                   // 36 m-tiles (even — 2x unroll relies on it)

typedef __bf16 bf16_t;
typedef bf16_t bf16x8 __attribute__((ext_vector_type(8)));
typedef bf16_t bf16x4 __attribute__((ext_vector_type(4)));
typedef float f32x4 __attribute__((ext_vector_type(4)));
typedef short short4v __attribute__((ext_vector_type(4)));

static __device__ __forceinline__ unsigned short f2bf(float f) {
    unsigned int u = __builtin_bit_cast(unsigned int, f);
    u += 0x7fffu + ((u >> 16) & 1u);
    return (unsigned short)(u >> 16);
}

static __device__ __forceinline__ f32x4 mfma16_bf16(short4v a, short4v b, f32x4 c) {
#if __has_builtin(__builtin_amdgcn_mfma_f32_16x16x16bf16_1k)
    return __builtin_amdgcn_mfma_f32_16x16x16bf16_1k(a, b, c, 0, 0, 0);
#else
    return c;  // host pass only — never executed on device
#endif
}

// async global->LDS DMA, 16B per lane. LDS dest must be linear.
static __device__ __forceinline__ void gl_lds16(const unsigned short* g, unsigned short* l) {
#if __has_builtin(__builtin_amdgcn_global_load_lds)
    __builtin_amdgcn_global_load_lds(
        (const __attribute__((address_space(1))) unsigned int*)(const void*)g,
        (__attribute__((address_space(3))) unsigned int*)(void*)l, 16, 0, 0);
#endif
}

static __device__ __forceinline__ void setprio1() {
#if __has_builtin(__builtin_amdgcn_s_setprio)
    __builtin_amdgcn_s_setprio(1);
#endif
}
static __device__ __forceinline__ void setprio0() {
#if __has_builtin(__builtin_amdgcn_s_setprio)
    __builtin_amdgcn_s_setprio(0);
#endif
}
static __device__ __forceinline__ void schedbar0() {
#if __has_builtin(__builtin_amdgcn_sched_barrier)
    __builtin_amdgcn_sched_barrier(0);
#endif
}
static __device__ __forceinline__ void rawbar() {
#if __has_builtin(__builtin_amdgcn_s_barrier)
    __builtin_amdgcn_s_barrier();
#else
    __syncthreads();
#endif
}

// ---------------- Kernel 1: fused pool(x,c2) + key conv + edge attention ----------------
__global__ __launch_bounds__(256) void prep_kernel(
    const float* __restrict__ x, const float* __restrict__ c2,
    const float* __restrict__ wq, const float* __restrict__ bq,
    const float* __restrict__ w1, const float* __restrict__ bnw, const float* __restrict__ bnb,
    const float* __restrict__ bnm, const float* __restrict__ bnv,
    const float* __restrict__ w2, const float* __restrict__ b2,
    unsigned short* __restrict__ kb, unsigned short* __restrict__ vb, float* __restrict__ ea) {

    __shared__ float lw1[OD_*2*C_];
    __shared__ float lwq[KD_*C_];
    __shared__ float xs[C_*33];
    __shared__ float c2s[C_*33];
    __shared__ float red[8][32];

    int tid = threadIdx.x;
    int b = blockIdx.x / 72;
    int m0 = (blockIdx.x % 72) * 32;

    for (int i = tid; i < OD_*2*C_; i += 256) lw1[i] = w1[i];
    for (int i = tid; i < KD_*C_; i += 256) lwq[i] = wq[i];
    for (int j = tid; j < 2048; j += 256) {
        int c = j >> 5, p = j & 31;
        int m = m0 + p;
        int hp = m / WP_, wp = m % WP_;
        size_t base = ((size_t)(b*C_ + c)*H_ + 2*hp)*W_ + 2*wp;
        const float* px = x + base;
        float mx = fmaxf(fmaxf(px[0], px[1]), fmaxf(px[W_], px[W_+1]));
        xs[c*33 + p] = mx;
        vb[(size_t)(b*C_ + c)*M_ + m] = f2bf(mx);
        const float* pc = c2 + base;
        c2s[c*33 + p] = fmaxf(fmaxf(pc[0], pc[1]), fmaxf(pc[W_], pc[W_+1]));
    }
    __syncthreads();

    int ml = tid & 31, oz = tid >> 5;
    int m = m0 + ml;

    float h[8] = {0,0,0,0,0,0,0,0};
    for (int c = 0; c < C_; c += 4) {
        float x0 = xs[c*33+ml], x1 = xs[(c+1)*33+ml], x2 = xs[(c+2)*33+ml], x3 = xs[(c+3)*33+ml];
        #pragma unroll
        for (int oi = 0; oi < 8; oi++) {
            const float4 wv = *(const float4*)&lwq[(oz*8 + oi)*C_ + c];
            h[oi] = fmaf(wv.x, x0, fmaf(wv.y, x1, fmaf(wv.z, x2, fmaf(wv.w, x3, h[oi]))));
        }
    }
    unsigned short tmp[8];
    #pragma unroll
    for (int oi = 0; oi < 8; oi++) tmp[oi] = f2bf(h[oi] + bq[oz*8 + oi]);
    *(uint4*)&kb[((size_t)b*M_ + m)*KD_ + oz*8] = *(const uint4*)tmp;

    float g[8] = {0,0,0,0,0,0,0,0};
    for (int c = 0; c < 2*C_; c += 4) {
        const float* srcb = (c < C_) ? &c2s[c*33] : &xs[(c - C_)*33];
        float x0 = srcb[ml], x1 = srcb[33+ml], x2 = srcb[66+ml], x3 = srcb[99+ml];
        #pragma unroll
        for (int oi = 0; oi < 8; oi++) {
            const float4 wv = *(const float4*)&lw1[(oz*8 + oi)*(2*C_) + c];
            g[oi] = fmaf(wv.x, x0, fmaf(wv.y, x1, fmaf(wv.z, x2, fmaf(wv.w, x3, g[oi]))));
        }
    }
    float z = 0.f;
    #pragma unroll
    for (int oi = 0; oi < 8; oi++) {
        int o = oz*8 + oi;
        float sc = bnw[o] * rsqrtf(bnv[o] + BN_EPS);
        float t = (g[oi] - bnm[o]) * sc + bnb[o];
        z += w2[o] * fmaxf(t, 0.f);
    }
    red[oz][ml] = z;
    __syncthreads();
    if (oz == 0) {
        float s = b2[0];
        #pragma unroll
        for (int i = 0; i < 8; i++) s += red[i][ml];
        ea[(size_t)b*M_ + m] = LOG2E / (1.f + __builtin_amdgcn_exp2f(-s * LOG2E));
    }
}

// ---------------- Kernel 2: flash attention with FUSED q-conv prologue ----------------
// R8: qk_kernel deleted. q is block-private (48 rows), so the q-conv fuses
// into attn's prologue duplication-free: w_q -> LDS (overlays buf0), fp32
// VALU conv (768 FMA/thread one-time), bf16 q -> LDS scratch (overlays buf1,
// ^(row&7) chunk swizzle), frag read, then the UNCHANGED R6 pipeline:
// register-level 1-deep frag pipeline + counted vmcnt + one barrier/step.
// R7's barrier-free per-wave layout is reverted (50us median + 41ms outlier).
__global__ __launch_bounds__(256, 3) void attn_kernel(
    const float* __restrict__ wq, const float* __restrict__ bq,
    const unsigned short* __restrict__ kb, const unsigned short* __restrict__ vb,
    const float* __restrict__ ea, const float* __restrict__ x,
    const float* __restrict__ gamma_p, float* __restrict__ out) {

    // dbuf: [k 8192 | v 8192] x2 = 32768 B, ea 9216 B -> 41984 B
    // prologue overlay: w_q 16KB in buf0, q-bf16 6KB at buf1 start
    // epilogue overlay: o_red 2*48*68*4=26112 + l_red 768 = 26880 B (fits)
    __shared__ __align__(16) char smem[41984];

    int tid = threadIdx.x;
    int wave = tid >> 6, lane = tid & 63, quad = lane >> 4, l16 = lane & 15;
    int blk = blockIdx.x;
    int b = (blk & 7) >> 1;                       // batch pinned to XCD pair
    int n_base = ((blk & 1) * (QB_/2) + (blk >> 3)) * QT_;
    int xsw = l16 & 7;

    // ---- fused q-conv (replaces qk_kernel) ----
    float* lwq = (float*)smem;                              // 16 KB (buf0)
    unsigned short* qlds = (unsigned short*)(smem + 16384); // 6 KB (buf1 start)
    for (int i = tid; i < KD_*C_; i += 256) lwq[i] = wq[i];
    __syncthreads();
    {
        const float* xb = x + (size_t)b*C_*N_ + n_base;
        // pass A: n_local = tid&31 (rows 0..31), channels (tid>>5)*8..+7
        {
            int ml = tid & 31, oz = tid >> 5;
            float h[8] = {0,0,0,0,0,0,0,0};
            const float* src = xb + ml;
            for (int c = 0; c < C_; c += 4) {
                float x0 = src[(size_t)c*N_], x1 = src[(size_t)(c+1)*N_];
                float x2 = src[(size_t)(c+2)*N_], x3 = src[(size_t)(c+3)*N_];
                #pragma unroll
                for (int oi = 0; oi < 8; oi++) {
                    const float4 wv = *(const float4*)&lwq[(oz*8 + oi)*C_ + c];
                    h[oi] = fmaf(wv.x, x0, fmaf(wv.y, x1, fmaf(wv.z, x2, fmaf(wv.w, x3, h[oi]))));
                }
            }
            unsigned short tmp[8];
            #pragma unroll
            for (int oi = 0; oi < 8; oi++) tmp[oi] = f2bf(h[oi] + bq[oz*8 + oi]);
            *(uint4*)&qlds[ml*64 + ((oz ^ (ml & 7)) << 3)] = *(const uint4*)tmp;
        }
        // pass B: n_local = 32 + (tid&15), channels (tid>>4)*4..+3
        {
            int ml = tid & 15, kq = tid >> 4;
            int n_l = 32 + ml;
            float h[4] = {0,0,0,0};
            const float* src = xb + n_l;
            for (int c = 0; c < C_; c += 4) {
                float x0 = src[(size_t)c*N_], x1 = src[(size_t)(c+1)*N_];
                float x2 = src[(size_t)(c+2)*N_], x3 = src[(size_t)(c+3)*N_];
                #pragma unroll
                for (int oi = 0; oi < 4; oi++) {
                    const float4 wv = *(const float4*)&lwq[(kq*4 + oi)*C_ + c];
                    h[oi] = fmaf(wv.x, x0, fmaf(wv.y, x1, fmaf(wv.z, x2, fmaf(wv.w, x3, h[oi]))));
                }
            }
            unsigned short tmp[4];
            #pragma unroll
            for (int oi = 0; oi < 4; oi++) tmp[oi] = f2bf(h[oi] + bq[kq*4 + oi]);
            *(uint2*)&qlds[n_l*64 + (((kq >> 1) ^ (n_l & 7)) << 3) + (kq & 1)*4] =
                *(const uint2*)tmp;
        }
    }
    __syncthreads();

    // Q B-frags from the swizzled LDS scratch: B[col=q=qi*16+l16][k=quad*8+j]
    bf16x8 qf[QI_][2];
    #pragma unroll
    for (int qi = 0; qi < QI_; qi++) {
        const unsigned short* qp = qlds + (qi*16 + l16)*64;
        qf[qi][0] = __builtin_bit_cast(bf16x8, *(const uint4*)(qp + ((quad     ^ xsw) << 3)));
        qf[qi][1] = __builtin_bit_cast(bf16x8, *(const uint4*)(qp + (((quad+4) ^ xsw) << 3)));
    }

    f32x4 o2[QI_][4]; // O^T partial: [qi][ct]
    f32x4 lacc[QI_];  // denominator partials via ones-MFMA
    #pragma unroll
    for (int qi = 0; qi < QI_; qi++) {
        lacc[qi] = (f32x4){0.f,0.f,0.f,0.f};
        #pragma unroll
        for (int ct = 0; ct < 4; ct++) o2[qi][ct] = (f32x4){0.f,0.f,0.f,0.f};
    }
    const short one_bf = (short)0x3F80;  // bf16 1.0
    short4v ones = (short4v){one_bf, one_bf, one_bf, one_bf};

    const unsigned short* kbB = kb + (size_t)b*M_*KD_;
    const unsigned short* vbB = vb + (size_t)b*C_*M_;
    const float* eaB = ea + (size_t)b*M_;

    int srow = tid >> 3;                       // 0..31
    int ksw  = ((tid & 7) ^ (srow & 7)) << 3;  // swizzled src offset (shorts)

    auto STAGE = [&](int mb, char* kd, char* vd) {
        unsigned short* kds = (unsigned short*)kd;
        unsigned short* vds = (unsigned short*)vd;
        gl_lds16(kbB + (size_t)(mb + srow)*KD_      + ksw, kds + tid*8);
        gl_lds16(kbB + (size_t)(mb + srow + 32)*KD_ + ksw, kds + 2048 + tid*8);
        gl_lds16(vbB + (size_t)srow*M_      + mb + ksw, vds + tid*8);
        gl_lds16(vbB + (size_t)(srow+32)*M_ + mb + ksw, vds + 2048 + tid*8);
    };

    // ---- ea -> LDS; then stage tiles 0+1 (frags already in regs, sync'd) ----
    {
        const f32x4* eaV = (const f32x4*)eaB;
        f32x4* eaL = (f32x4*)(smem + 32768);
        for (int i = tid; i < M_/4; i += 256) eaL[i] = eaV[i];
    }
    asm volatile("s_waitcnt lgkmcnt(0)" ::: "memory"); // qf reads + ea ds_writes done
    __syncthreads();                                   // all waves done with qlds/w_q
    STAGE(0,  smem,          smem + 8192);
    STAGE(64, smem + 16384,  smem + 16384 + 8192);
    asm volatile("s_waitcnt vmcnt(4)" ::: "memory");   // tile0 DMA done (own wave)
    rawbar();                                          // => all waves' tile0 done
    asm volatile("" ::: "memory");

    const float* lds_ea = (const float*)(smem + 32768);
    int krow = wave*16 + l16;

    // frag double-buffer: two NAMED sets (constant field access only)
    struct FragSet { bf16x8 kf0, kf1; short4v va0, va1, va2, va3; f32x4 e4; };
    FragSet fA, fB;

    // read frag set for tile 0 into fA (from buf0)
    {
        unsigned short* kc = (unsigned short*)smem;
        unsigned short* vc = (unsigned short*)(smem + 8192);
        fA.e4  = *(const f32x4*)&lds_ea[0*64 + wave*16 + quad*4];
        fA.kf0 = __builtin_bit_cast(bf16x8, *(const uint4*)(kc + krow*KD_ + (((quad  ) ^ xsw) << 3)));
        fA.kf1 = __builtin_bit_cast(bf16x8, *(const uint4*)(kc + krow*KD_ + (((quad+4) ^ xsw) << 3)));
        fA.va0 = *(const short4v*)(vc + (0*16 + l16)*64 + (((wave*2 + (quad>>1)) ^ xsw) << 3) + (quad&1)*4);
        fA.va1 = *(const short4v*)(vc + (1*16 + l16)*64 + (((wave*2 + (quad>>1)) ^ xsw) << 3) + (quad&1)*4);
        fA.va2 = *(const short4v*)(vc + (2*16 + l16)*64 + (((wave*2 + (quad>>1)) ^ xsw) << 3) + (quad&1)*4);
        fA.va3 = *(const short4v*)(vc + (3*16 + l16)*64 + (((wave*2 + (quad>>1)) ^ xsw) << 3) + (quad&1)*4);
    }

// one pipeline step: compute tile T_ from CUR; prefetch T_+1 frags into NXT
#define ATTN_STEP(T_, CUR, NXT)                                                        \
    {                                                                                  \
        const int t_ = (T_);                                                           \
        if (t_ < NT_ - 1) {                                                            \
            asm volatile("s_waitcnt vmcnt(0)" ::: "memory");  /* tile t_+1 DMA done */ \
            schedbar0();                                                               \
            rawbar();                               /* acquire buf[(t_+1)&1], release buf[t_&1] */ \
            asm volatile("" ::: "memory");                                             \
            schedbar0();                                                               \
            if (t_ + 2 < NT_) {                                                        \
                char* nb = smem + (t_ & 1) * 16384;                                    \
                STAGE((t_ + 2) * 64, nb, nb + 8192);                                   \
            }                                                                          \
            unsigned short* kc_ = (unsigned short*)(smem + ((t_ + 1) & 1) * 16384);    \
            unsigned short* vc_ = (unsigned short*)(smem + ((t_ + 1) & 1) * 16384 + 8192); \
            NXT.e4  = *(const f32x4*)&lds_ea[(t_ + 1)*64 + wave*16 + quad*4];          \
            NXT.kf0 = __builtin_bit_cast(bf16x8, *(const uint4*)(kc_ + krow*KD_ + (((quad  ) ^ xsw) << 3))); \
            NXT.kf1 = __builtin_bit_cast(bf16x8, *(const uint4*)(kc_ + krow*KD_ + (((quad+4) ^ xsw) << 3))); \
            NXT.va0 = *(const short4v*)(vc_ + (0*16 + l16)*64 + (((wave*2 + (quad>>1)) ^ xsw) << 3) + (quad&1)*4); \
            NXT.va1 = *(const short4v*)(vc_ + (1*16 + l16)*64 + (((wave*2 + (quad>>1)) ^ xsw) << 3) + (quad&1)*4); \
            NXT.va2 = *(const short4v*)(vc_ + (2*16 + l16)*64 + (((wave*2 + (quad>>1)) ^ xsw) << 3) + (quad&1)*4); \
            NXT.va3 = *(const short4v*)(vc_ + (3*16 + l16)*64 + (((wave*2 + (quad>>1)) ^ xsw) << 3) + (quad&1)*4); \
            schedbar0();                                                               \
            asm volatile("s_waitcnt lgkmcnt(7)" ::: "memory"); /* CUR reads landed */  \
            schedbar0();                                                               \
        } else {                                                                       \
            schedbar0();                                                               \
            asm volatile("s_waitcnt lgkmcnt(0)" ::: "memory"); /* last frag set */     \
            schedbar0();                                                               \
        }                                                                              \
        /* ---- compute tile t_ from CUR (register-only) ---- */                       \
        f32x4 st[QI_];                                                                 \
        setprio1();                                                                    \
        _Pragma("unroll")                                                              \
        for (int qi = 0; qi < QI_; qi++) {                                             \
            f32x4 z = (f32x4){0.f,0.f,0.f,0.f};                                        \
            z = __builtin_amdgcn_mfma_f32_16x16x32_bf16(CUR.kf0, qf[qi][0], z, 0, 0, 0); \
            z = __builtin_amdgcn_mfma_f32_16x16x32_bf16(CUR.kf1, qf[qi][1], z, 0, 0, 0); \
            st[qi] = z;                                                                \
        }                                                                              \
        setprio0();                                                                    \
        short4v pk[QI_];                                                               \
        _Pragma("unroll")                                                              \
        for (int qi = 0; qi < QI_; qi++) {                                             \
            f32x4 p;                                                                   \
            p[0] = __builtin_amdgcn_exp2f(fmaf(st[qi][0], CUR.e4[0], -SHIFT2));        \
            p[1] = __builtin_amdgcn_exp2f(fmaf(st[qi][1], CUR.e4[1], -SHIFT2));        \
            p[2] = __builtin_amdgcn_exp2f(fmaf(st[qi][2], CUR.e4[2], -SHIFT2));        \
            p[3] = __builtin_amdgcn_exp2f(fmaf(st[qi][3], CUR.e4[3], -SHIFT2));        \
            pk[qi] = __builtin_bit_cast(short4v, __builtin_convertvector(p, bf16x4));  \
        }                                                                              \
        setprio1();                                                                    \
        _Pragma("unroll")                                                              \
        for (int qi = 0; qi < QI_; qi++) {                                             \
            o2[qi][0] = mfma16_bf16(CUR.va0, pk[qi], o2[qi][0]);                       \
            o2[qi][1] = mfma16_bf16(CUR.va1, pk[qi], o2[qi][1]);                       \
            o2[qi][2] = mfma16_bf16(CUR.va2, pk[qi], o2[qi][2]);                       \
            o2[qi][3] = mfma16_bf16(CUR.va3, pk[qi], o2[qi][3]);                       \
            lacc[qi]  = mfma16_bf16(ones,    pk[qi], lacc[qi]);                        \
        }                                                                              \
        setprio0();                                                                    \
    }

    for (int t = 0; t < NT_; t += 2) {
        ATTN_STEP(t,     fA, fB);
        ATTN_STEP(t + 1, fB, fA);
    }
#undef ATTN_STEP

    __syncthreads();   // all waves done with LDS K/V buffers before overlay

    // ---- epilogue: cross-wave reduction of O^T partials and denominators ----
    float* o_red0 = (float*)smem;            // [48 q][68 c]
    float* o_red1 = o_red0 + QT_*68;
    float* l_red  = o_red1 + QT_*68;         // [4][48]

    if (lane < 16) {
        #pragma unroll
        for (int qi = 0; qi < QI_; qi++) l_red[wave*QT_ + qi*16 + l16] = lacc[qi][0];
    }
    if (wave < 2) {
        float* od = (wave == 0) ? o_red0 : o_red1;
        #pragma unroll
        for (int qi = 0; qi < QI_; qi++)
            #pragma unroll
            for (int ct = 0; ct < 4; ct++)
                *(f32x4*)&od[(qi*16 + l16)*68 + ct*16 + quad*4] = o2[qi][ct];
    }
    __syncthreads();
    if (wave >= 2) {
        float* od = (wave == 2) ? o_red0 : o_red1;
        #pragma unroll
        for (int qi = 0; qi < QI_; qi++)
            #pragma unroll
            for (int ct = 0; ct < 4; ct++) {
                f32x4* p = (f32x4*)&od[(qi*16 + l16)*68 + ct*16 + quad*4];
                *p += o2[qi][ct];
            }
    }
    __syncthreads();
    if (tid < QT_) {
        float s = (l_red[tid] + l_red[QT_ + tid]) + (l_red[2*QT_ + tid] + l_red[3*QT_ + tid]);
        l_red[tid] = 1.f / s;
    }
    __syncthreads();

    float gmm = gamma_p[0];
    int c = tid >> 2, q4 = tid & 3;
    const float* xrow = x + ((size_t)b*C_ + c)*N_ + n_base;
    float* orow = out + ((size_t)b*C_ + c)*N_ + n_base;
    #pragma unroll
    for (int i = 0; i < QI_; i++) {
        int q0 = q4*4 + i*16;
        float4 xv = *(const float4*)(xrow + q0);
        float4 ov;
        float v0 = (o_red0[(q0+0)*68 + c] + o_red1[(q0+0)*68 + c]) * l_red[q0+0];
        float v1 = (o_red0[(q0+1)*68 + c] + o_red1[(q0+1)*68 + c]) * l_red[q0+1];
        float v2 = (o_red0[(q0+2)*68 + c] + o_red1[(q0+2)*68 + c]) * l_red[q0+2];
        float v3 = (o_red0[(q0+3)*68 + c] + o_red1[(q0+3)*68 + c]) * l_red[q0+3];
        ov.x = fmaf(gmm, v0, xv.x);
        ov.y = fmaf(gmm, v1, xv.y);
        ov.z = fmaf(gmm, v2, xv.z);
        ov.w = fmaf(gmm, v3, xv.w);
        *(float4*)(orow + q0) = ov;
    }
}

extern "C" void kernel_launch(void* const* d_in, const int* in_sizes, int n_in,
                              void* d_out, int out_size, void* d_ws, size_t ws_size,
                              hipStream_t stream) {
    const float* c2    = (const float*)d_in[0];
    const float* x     = (const float*)d_in[1];
    const float* w_ea1 = (const float*)d_in[2];
    const float* bn_w  = (const float*)d_in[3];
    const float* bn_b  = (const float*)d_in[4];
    const float* bn_m  = (const float*)d_in[5];
    const float* bn_v  = (const float*)d_in[6];
    const float* w_ea2 = (const float*)d_in[7];
    const float* b_ea2 = (const float*)d_in[8];
    const float* w_q   = (const float*)d_in[9];
    const float* b_q   = (const float*)d_in[10];
    const float* gamma = (const float*)d_in[11];
    float* out = (float*)d_out;

    char* ws = (char*)d_ws;
    float* ea            = (float*)(ws + 0);                // 36864 B
    unsigned short* kb   = (unsigned short*)(ws + 36864);   // 1179648 B
    unsigned short* vb   = (unsigned short*)(ws + 1216512); // 1179648 B

    prep_kernel<<<dim3((B_*M_)/32), dim3(256), 0, stream>>>(x, c2, w_q, b_q,
        w_ea1, bn_w, bn_b, bn_m, bn_v, w_ea2, b_ea2, kb, vb, ea);
    attn_kernel<<<dim3(B_*QB_), dim3(256), 0, stream>>>(w_q, b_q, kb, vb, ea, x, gamma, out);
}